// Round 1
// baseline (92.579 us; speedup 1.0000x reference)
//
#include <hip/hip_runtime.h>
#include <math.h>

#define BB   8
#define NN   96
#define DD   16
#define H0D  50
#define H1D  50
#define OUTD 64
#define XPAD 17      // padded row stride for x tiles in LDS
#define APAD 97      // padded row stride for adj tile in LDS

// W1: (51,50) row-major. rows 0-15 Wxi, 16-31 Wxj, 32-47 Wxk, 48 w_ij, 49 w_jk, 50 w_ik
// W2: (83,50), W3: (66,64)

__global__ __launch_bounds__(128) void k1_precompute(
    const float* __restrict__ x, const float* __restrict__ adj,
    const float* __restrict__ W1,
    float* __restrict__ dis, float* __restrict__ deg, float* __restrict__ sdjk,
    float* __restrict__ nx, float* __restrict__ A, float* __restrict__ Bm,
    float* __restrict__ sumC)
{
    const int b = blockIdx.x / NN, r = blockIdx.x % NN;
    const int tid = threadIdx.x;
    __shared__ float sx[NN * XPAD];
    __shared__ float sadj[NN];
    __shared__ float sdis[NN];
    __shared__ float snx[DD];

    for (int idx = tid; idx < NN * DD; idx += 128)
        sx[(idx / DD) * XPAD + (idx % DD)] = x[b * NN * DD + idx];
    if (tid < NN) sadj[tid] = adj[(b * NN + r) * NN + tid];
    __syncthreads();

    if (tid < NN) {
        float s = 1e-10f;
        #pragma unroll
        for (int d = 0; d < DD; ++d) {
            float t = sx[r * XPAD + d] - sx[tid * XPAD + d];
            s += t * t;
        }
        float dv = sqrtf(s);
        sdis[tid] = dv;
        dis[(b * NN + r) * NN + tid] = dv;
    }
    __syncthreads();

    if (tid < DD) {
        float s = 0.f;
        for (int k = 0; k < NN; ++k) s += sadj[k] * sx[k * XPAD + tid];
        snx[tid] = s;
        nx[(b * NN + r) * DD + tid] = s;
    } else if (tid == DD) {
        float s = 0.f;
        for (int k = 0; k < NN; ++k) s += sadj[k];
        deg[b * NN + r] = s;
    } else if (tid == DD + 1) {
        float s = 0.f;
        for (int k = 0; k < NN; ++k) s += sadj[k] * sdis[k];
        sdjk[b * NN + r] = s;
    }
    __syncthreads();

    if (tid < H0D) {
        float a = 0.f, bm = 0.f, sc = 0.f;
        #pragma unroll
        for (int d = 0; d < DD; ++d) {
            float xr = sx[r * XPAD + d];
            a  += xr * W1[d * H0D + tid];
            bm += xr * W1[(DD + d) * H0D + tid];
            sc += snx[d] * W1[(2 * DD + d) * H0D + tid];
        }
        int o = (b * NN + r) * H0D + tid;
        A[o] = a; Bm[o] = bm; sumC[o] = sc;
    }
}

__global__ __launch_bounds__(128) void k2_main(
    const float* __restrict__ x, const float* __restrict__ adj,
    const float* __restrict__ W1, const float* __restrict__ b1,
    const float* __restrict__ W2, const float* __restrict__ b2,
    const float* __restrict__ W3, const float* __restrict__ b3,
    const float* __restrict__ dis, const float* __restrict__ deg,
    const float* __restrict__ sdjk, const float* __restrict__ nx,
    const float* __restrict__ A, const float* __restrict__ Bm,
    const float* __restrict__ sumC, float* __restrict__ out)
{
    const int b = blockIdx.x / NN, i = blockIdx.x % NN;
    const int tid = threadIdx.x;
    __shared__ float sAdj[NN * APAD];   // full adj[b], padded
    __shared__ float sdis[NN];
    __shared__ float sdik[NN];
    __shared__ float sagg[96];          // 83 used
    __shared__ float sm2s[H1D];

    for (int idx = tid; idx < NN * NN; idx += 128)
        sAdj[(idx / NN) * APAD + (idx % NN)] = adj[b * NN * NN + idx];
    if (tid < NN) sdis[tid] = dis[(b * NN + i) * NN + tid];
    __syncthreads();

    // sd_ik[b,i,j] = sum_k dis[b,i,k] * adj[b,j,k]
    if (tid < NN) {
        float s = 0.f;
        const float* row = &sAdj[tid * APAD];
        for (int k = 0; k < NN; ++k) s += sdis[k] * row[k];
        sdik[tid] = s;
    }
    __syncthreads();

    // per-channel neighbor accumulation: msum_h = sum_j adj_ij * leaky(adj_ij * S_ijh)
    float msum = 0.f;
    float a_ih = 0.f, b1h = 0.f, wij = 0.f, wjk = 0.f, wik = 0.f;
    if (tid < H0D) {
        a_ih = A[(b * NN + i) * H0D + tid];
        b1h = b1[tid];
        wij = W1[(3 * DD + 0) * H0D + tid];
        wjk = W1[(3 * DD + 1) * H0D + tid];
        wik = W1[(3 * DD + 2) * H0D + tid];
    }
    for (int j = 0; j < NN; ++j) {
        float aij = sAdj[i * APAD + j];   // wave-uniform broadcast
        if (aij == 0.f) continue;
        if (tid < H0D) {
            float degj  = deg[b * NN + j];
            float sdjkj = sdjk[b * NN + j];
            float bmjh = Bm[(b * NN + j) * H0D + tid];
            float scjh = sumC[(b * NN + j) * H0D + tid];
            float S = degj * (a_ih + bmjh + b1h + sdis[j] * wij)
                    + scjh + sdjkj * wjk + sdik[j] * wik;
            float v = aij * S;
            v = (v >= 0.f) ? v : 0.05f * v;
            msum += aij * v;
        }
    }

    // build aggregated feat2 sum (83 elems)
    float degi = deg[b * NN + i];
    if (tid < H0D) sagg[33 + tid] = msum;
    if (tid < DD) sagg[tid] = degi * x[(b * NN + i) * DD + tid];
    else if (tid < 2 * DD) sagg[tid] = nx[(b * NN + i) * DD + (tid - DD)];
    else if (tid == 2 * DD) sagg[tid] = sdjk[b * NN + i];
    __syncthreads();

    if (tid < H1D) {
        float s = degi * b2[tid];
        for (int c = 0; c < 2 * DD + H0D + 1; ++c)
            s += sagg[c] * W2[c * H1D + tid];
        s = (s >= 0.f) ? s : 0.05f * s;
        sm2s[tid] = s;
    }
    __syncthreads();

    if (tid < OUTD) {
        float s = b3[tid];
        #pragma unroll
        for (int d = 0; d < DD; ++d)
            s += x[(b * NN + i) * DD + d] * W3[d * OUTD + tid];
        for (int h = 0; h < H1D; ++h)
            s += sm2s[h] * W3[(DD + h) * OUTD + tid];
        s = (s >= 0.f) ? s : 0.05f * s;
        out[(b * NN + i) * OUTD + tid] = s;
    }
}

extern "C" void kernel_launch(void* const* d_in, const int* in_sizes, int n_in,
                              void* d_out, int out_size, void* d_ws, size_t ws_size,
                              hipStream_t stream) {
    const float* x   = (const float*)d_in[0];
    const float* adj = (const float*)d_in[1];
    const float* W1  = (const float*)d_in[2];
    const float* b1  = (const float*)d_in[3];
    const float* W2  = (const float*)d_in[4];
    const float* b2  = (const float*)d_in[5];
    const float* W3  = (const float*)d_in[6];
    const float* b3  = (const float*)d_in[7];
    float* out = (float*)d_out;

    float* ws   = (float*)d_ws;
    float* dis  = ws;                 // 8*96*96   = 73728
    float* deg  = dis + BB * NN * NN; // 768
    float* sdjk = deg + BB * NN;      // 768
    float* nx   = sdjk + BB * NN;     // 8*96*16   = 12288
    float* A    = nx + BB * NN * DD;  // 8*96*50   = 38400
    float* Bm   = A + BB * NN * H0D;  // 38400
    float* sumC = Bm + BB * NN * H0D; // 38400

    k1_precompute<<<BB * NN, 128, 0, stream>>>(x, adj, W1, dis, deg, sdjk, nx, A, Bm, sumC);
    k2_main<<<BB * NN, 128, 0, stream>>>(x, adj, W1, b1, W2, b2, W3, b3,
                                         dis, deg, sdjk, nx, A, Bm, sumC, out);
}